// Round 3
// baseline (277.943 us; speedup 1.0000x reference)
//
#include <hip/hip_runtime.h>
#include <math.h>

#define HW_   128
#define CIN_  64
#define IMG_  (HW_ * HW_)       // 16384

typedef short  s16x8 __attribute__((ext_vector_type(8)));
typedef float  f32x4 __attribute__((ext_vector_type(4)));

__device__ __forceinline__ float bf2f(short u) {
  union { unsigned i; float f; } v;
  v.i = ((unsigned)(unsigned short)u) << 16;
  return v.f;
}
__device__ __forceinline__ short f2bf(float f) {
  union { float f; unsigned i; } v; v.f = f;
  unsigned r = (v.i + 0x7fffu + ((v.i >> 16) & 1u)) >> 16;   // RNE
  return (short)r;
}
// pack two f32 -> bf16 pair (lo = a, hi = b), RNE, via v_perm
__device__ __forceinline__ unsigned pk_bf16(float a, float b) {
  union { float f; unsigned u; } ua, ub; ua.f = a; ub.f = b;
  unsigned ra = ua.u + 0x7fffu + ((ua.u >> 16) & 1u);
  unsigned rb = ub.u + 0x7fffu + ((ub.u >> 16) & 1u);
  return __builtin_amdgcn_perm(rb, ra, 0x07060302u);
}

// ws layout (bytes):
//   [0,       36864)   wofb [32][576] bf16 : wofb[m][j*64+c] = w_off[m][c][kh][kw], rows 27..31 = 0
//   [36864,  110592)   wcb  [64][576] bf16 : wcb[o][j*64+c]  = w_conv[o][c*9+j]
//   [110592, 7188480)  offbuf [8][27][16384] bf16 : o1(0-8), o2(9-17), sigmoid(mask)(18-26)
//   [7188480, ...)     G [cb][9][16384][64] bf16, chunked by batch to fit ws_size

__global__ __launch_bounds__(256) void prep_w(const float* __restrict__ w_off,
                                              const float* __restrict__ w_conv,
                                              short* __restrict__ wofb,
                                              short* __restrict__ wcb) {
  int t = blockIdx.x * 256 + threadIdx.x;
  if (t < 64 * 576) {
    int o = t / 576, k = t - o * 576;
    int j = k >> 6, c = k & 63;
    wcb[t] = f2bf(w_conv[o * 576 + c * 9 + j]);
  }
  if (t < 32 * 576) {
    int m = t / 576, k = t - m * 576;
    int j = k >> 6, c = k & 63;
    wofb[t] = (m < 27) ? f2bf(w_off[m * 576 + c * 9 + j]) : (short)0;
  }
}

// offset conv: halo tile staged ONCE (1 barrier), then 9 taps x 4 MFMA.
__global__ __launch_bounds__(256) void offc2(const float* __restrict__ x,
                                             const short* __restrict__ wofb,
                                             const float* __restrict__ b_off,
                                             short* __restrict__ offbuf) {
  __shared__ short tile[3 * 66 * 72];   // [row 3][px 66][ch 64, pitch 72] bf16
  int bi  = blockIdx.x >> 8;
  int hw0 = (blockIdx.x & 255) * 64;
  int h   = hw0 >> 7;
  int w0  = hw0 & 127;
  int t   = threadIdx.x;

  const float* xb = x + bi * (CIN_ * IMG_);
  // stage halo: rows h-1..h+1, px w0-1..w0+64, all 64 ch (pairs -> b32 writes)
  for (int idx = t; idx < 3 * 66 * 32; idx += 256) {
    int p  = idx % 66;
    int rc = idx / 66;
    int r  = rc % 3;
    int c0 = (rc / 3) * 2;
    int hh = h + r - 1, ww = w0 + p - 1;
    unsigned pkv = 0;
    if (hh >= 0 && hh < HW_ && ww >= 0 && ww < HW_) {
      float f0 = xb[c0 * IMG_ + hh * HW_ + ww];
      float f1 = xb[(c0 + 1) * IMG_ + hh * HW_ + ww];
      pkv = pk_bf16(f0, f1);
    }
    *(unsigned*)&tile[(r * 66 + p) * 72 + c0] = pkv;
  }
  __syncthreads();

  int wv = t >> 6, l = t & 63;
  int col = l & 15, q = l >> 4;
  int px_local = wv * 16 + col;

  f32x4 acc0 = {0.f, 0.f, 0.f, 0.f};
  f32x4 acc1 = {0.f, 0.f, 0.f, 0.f};
#pragma unroll
  for (int j = 0; j < 9; ++j) {
    int dy = j / 3, dx = j % 3;
#pragma unroll
    for (int ks = 0; ks < 2; ++ks) {
      s16x8 bf = *(const s16x8*)&tile[(dy * 66 + px_local + dx) * 72 + ks * 32 + q * 8];
      s16x8 a0 = *(const s16x8*)(wofb + (col)      * 576 + j * 64 + ks * 32 + q * 8);
      s16x8 a1 = *(const s16x8*)(wofb + (16 + col) * 576 + j * 64 + ks * 32 + q * 8);
      acc0 = __builtin_amdgcn_mfma_f32_16x16x32_bf16(a0, bf, acc0, 0, 0, 0);
      acc1 = __builtin_amdgcn_mfma_f32_16x16x32_bf16(a1, bf, acc1, 0, 0, 0);
    }
  }

  short* ob = offbuf + bi * (27 * IMG_) + hw0 + px_local;
#pragma unroll
  for (int r = 0; r < 4; ++r) {
    int ch = q * 4 + r;
    float v = acc0[r] + b_off[ch];
    if (ch >= 18) v = 1.f / (1.f + __expf(-v));
    ob[ch * IMG_] = f2bf(v);
  }
#pragma unroll
  for (int r = 0; r < 4; ++r) {
    int ch = 16 + q * 4 + r;
    if (ch < 27) {
      float v = acc1[r] + b_off[ch];
      if (ch >= 18) v = 1.f / (1.f + __expf(-v));
      ob[ch * IMG_] = f2bf(v);
    }
  }
}

// G[bl][j][p][o] = sum_c wcb[o][j*64+c] * x[bi][c][p]  (bf16 MFMA, no K-loop barrier)
__global__ __launch_bounds__(256) void tapgemm(const float* __restrict__ x,
                                               const short* __restrict__ wcb,
                                               short* __restrict__ G,
                                               int b0) {
  __shared__ short tl[64 * 72];        // [px 64][ch 64, pitch 72] bf16
  int bl  = blockIdx.x >> 8;
  int bi  = b0 + bl;
  int hw0 = (blockIdx.x & 255) * 64;
  int t   = threadIdx.x;

  const float* xb = x + bi * (CIN_ * IMG_) + hw0;
#pragma unroll
  for (int ii = 0; ii < 8; ++ii) {
    int c0 = (ii * 4 + (t >> 6)) * 2;
    int px = t & 63;
    float f0 = xb[c0 * IMG_ + px];
    float f1 = xb[(c0 + 1) * IMG_ + px];
    *(unsigned*)&tl[px * 72 + c0] = pk_bf16(f0, f1);
  }
  __syncthreads();

  int wv = t >> 6, l = t & 63;
  int col = l & 15, q = l >> 4;
  int px_local = wv * 16 + col;
  int p = hw0 + px_local;

  s16x8 b0f = *(const s16x8*)&tl[px_local * 72 + q * 8];
  s16x8 b1f = *(const s16x8*)&tl[px_local * 72 + 32 + q * 8];

#pragma unroll
  for (int j = 0; j < 9; ++j) {
    f32x4 acc[4];
#pragma unroll
    for (int ms = 0; ms < 4; ++ms) acc[ms] = (f32x4){0.f, 0.f, 0.f, 0.f};
#pragma unroll
    for (int ms = 0; ms < 4; ++ms) {
      s16x8 a0 = *(const s16x8*)(wcb + (ms * 16 + col) * 576 + j * 64 + q * 8);
      s16x8 a1 = *(const s16x8*)(wcb + (ms * 16 + col) * 576 + j * 64 + 32 + q * 8);
      acc[ms] = __builtin_amdgcn_mfma_f32_16x16x32_bf16(a0, b0f, acc[ms], 0, 0, 0);
      acc[ms] = __builtin_amdgcn_mfma_f32_16x16x32_bf16(a1, b1f, acc[ms], 0, 0, 0);
    }
    short* gp = G + ((bl * 9 + j) * IMG_ + p) * 64;
#pragma unroll
    for (int ms = 0; ms < 4; ++ms) {
      uint2 dd;
      dd.x = pk_bf16(acc[ms][0], acc[ms][1]);
      dd.y = pk_bf16(acc[ms][2], acc[ms][3]);
      *(uint2*)(gp + ms * 16 + q * 4) = dd;
    }
  }
}

// gather G at 4 bilinear corners per tap, weighted-add into 16 fp32 acc, store NCHW.
__global__ __launch_bounds__(256) void sampler(const short* __restrict__ G,
                                               const short* __restrict__ offbuf,
                                               float* __restrict__ out,
                                               int b0) {
  int bl  = blockIdx.x >> 8;
  int bi  = b0 + bl;
  int hw0 = (blockIdx.x & 255) * 64;
  int t   = threadIdx.x;
  int q   = t & 3;                 // 16-ch slice; 4 lanes share a pixel
  int px_local = t >> 2;
  int p   = hw0 + px_local;
  int h   = p >> 7, w = p & 127;

  const short* ob = offbuf + bi * (27 * IMG_) + p;
  const short* Gb = G + (bl * 9) * (IMG_ * 64) + q * 16;

  float acc[16];
#pragma unroll
  for (int i = 0; i < 16; ++i) acc[i] = 0.f;

  for (int j = 0; j < 9; ++j) {
    float o1 = bf2f(ob[j * IMG_]);
    float o2 = bf2f(ob[(9 + j) * IMG_]);
    float mk = bf2f(ob[(18 + j) * IMG_]);

    float pxf = o1 + (float)(w + (j % 3) - 1);
    float pyf = o2 + (float)(h + (j / 3) - 1);
    float fx = floorf(pxf), fy = floorf(pyf);
    int   x0 = (int)fx,   y0 = (int)fy;
    float ax = pxf - fx, ay = pyf - fy;
    float bx = 1.f - ax, by = 1.f - ay;

    bool vx0 = (x0 >= 0)  && (x0 < HW_);
    bool vx1 = (x0 >= -1) && (x0 < HW_ - 1);
    bool vy0 = (y0 >= 0)  && (y0 < HW_);
    bool vy1 = (y0 >= -1) && (y0 < HW_ - 1);

    float w00 = by * bx * mk * ((vy0 && vx0) ? 1.f : 0.f);
    float w01 = by * ax * mk * ((vy0 && vx1) ? 1.f : 0.f);
    float w10 = ay * bx * mk * ((vy1 && vx0) ? 1.f : 0.f);
    float w11 = ay * ax * mk * ((vy1 && vx1) ? 1.f : 0.f);

    int xc0 = min(max(x0, 0), HW_ - 1), xc1 = min(max(x0 + 1, 0), HW_ - 1);
    int yc0 = min(max(y0, 0), HW_ - 1), yc1 = min(max(y0 + 1, 0), HW_ - 1);

    const short* Gj = Gb + j * (IMG_ * 64);
    const short* p00 = Gj + (yc0 * HW_ + xc0) * 64;
    const short* p01 = Gj + (yc0 * HW_ + xc1) * 64;
    const short* p10 = Gj + (yc1 * HW_ + xc0) * 64;
    const short* p11 = Gj + (yc1 * HW_ + xc1) * 64;

    const short* ptrs[4] = {p00, p01, p10, p11};
    float        wts[4]  = {w00, w01, w10, w11};
#pragma unroll
    for (int cn = 0; cn < 4; ++cn) {
      uint4 a = *(const uint4*)(ptrs[cn]);
      uint4 b = *(const uint4*)(ptrs[cn] + 8);
      unsigned d[8] = {a.x, a.y, a.z, a.w, b.x, b.y, b.z, b.w};
      float wgt = wts[cn];
#pragma unroll
      for (int k = 0; k < 8; ++k) {
        union { unsigned u; float f; } lo, hi;
        lo.u = d[k] << 16;
        hi.u = d[k] & 0xffff0000u;
        acc[2 * k]     = fmaf(wgt, lo.f, acc[2 * k]);
        acc[2 * k + 1] = fmaf(wgt, hi.f, acc[2 * k + 1]);
      }
    }
  }

  float* op = out + bi * (CIN_ * IMG_) + p;
#pragma unroll
  for (int i = 0; i < 16; ++i)
    op[(q * 16 + i) * IMG_] = acc[i];
}

extern "C" void kernel_launch(void* const* d_in, const int* in_sizes, int n_in,
                              void* d_out, int out_size, void* d_ws, size_t ws_size,
                              hipStream_t stream) {
  const float* x      = (const float*)d_in[0];
  const float* w_off  = (const float*)d_in[1];
  const float* b_off  = (const float*)d_in[2];
  const float* w_conv = (const float*)d_in[3];
  float* out = (float*)d_out;

  char* ws = (char*)d_ws;
  short* wofb   = (short*)(ws);
  short* wcb    = (short*)(ws + 36864);
  short* offbuf = (short*)(ws + 110592);
  short* G      = (short*)(ws + 7188480);

  const size_t g_per_batch = (size_t)9 * IMG_ * 64 * 2;  // 18874368
  long avail = (long)ws_size - 7188480L;
  int cb = (int)(avail / (long)g_per_batch);
  if (cb > 8) cb = 8;
  if (cb < 1) cb = 1;

  hipLaunchKernelGGL(prep_w, dim3(144),  dim3(256), 0, stream, w_off, w_conv, wofb, wcb);
  hipLaunchKernelGGL(offc2,  dim3(2048), dim3(256), 0, stream, x, wofb, b_off, offbuf);
  for (int b0 = 0; b0 < 8; b0 += cb) {
    int nb = (8 - b0 < cb) ? (8 - b0) : cb;
    hipLaunchKernelGGL(tapgemm, dim3(nb * 256), dim3(256), 0, stream, x, wcb, G, b0);
    hipLaunchKernelGGL(sampler, dim3(nb * 256), dim3(256), 0, stream, G, offbuf, out, b0);
  }
}

// Round 4
// 199.092 us; speedup vs baseline: 1.3961x; 1.3961x over previous
//
#include <hip/hip_runtime.h>
#include <math.h>

#define HW_   128
#define CIN_  64
#define IMG_  (HW_ * HW_)       // 16384

typedef short  s16x8 __attribute__((ext_vector_type(8)));
typedef float  f32x4 __attribute__((ext_vector_type(4)));

__device__ __forceinline__ float bf2f(short u) {
  union { unsigned i; float f; } v;
  v.i = ((unsigned)(unsigned short)u) << 16;
  return v.f;
}
__device__ __forceinline__ short f2bf(float f) {
  union { float f; unsigned i; } v; v.f = f;
  unsigned r = (v.i + 0x7fffu + ((v.i >> 16) & 1u)) >> 16;   // RNE
  return (short)r;
}
// pack two f32 -> bf16 pair (lo = a, hi = b), RNE
__device__ __forceinline__ unsigned pk_bf16(float a, float b) {
  union { float f; unsigned u; } ua, ub; ua.f = a; ub.f = b;
  unsigned ra = ua.u + 0x7fffu + ((ua.u >> 16) & 1u);
  unsigned rb = ub.u + 0x7fffu + ((ub.u >> 16) & 1u);
  return __builtin_amdgcn_perm(rb, ra, 0x07060302u);
}

// ws layout (bytes):
//   [0,       36864)    wOf bf16 [j:9][ks:2][q:4][m:32][i:8]  (A-frag order, m>=27 zero)
//   [36864,   110592)   wA  bf16 [j:9][ks:2][q:4][o:64][i:8]  (A-frag order)
//   [110592,  8499200)  ob2 bf16 [8][16384][32] pixel-major: o1(0-8) o2(9-17) sig(mask)(18-26)
//   [8499200, 25276416) x_t bf16 [8][128][128][64] (NHWC)

__global__ __launch_bounds__(256) void prep_w(const float* __restrict__ w_off,
                                              const float* __restrict__ w_conv,
                                              short* __restrict__ wOf,
                                              short* __restrict__ wA) {
  int t = blockIdx.x * 256 + threadIdx.x;
  if (t < 36864) {
    int i = t & 7, o = (t >> 3) & 63, q = (t >> 9) & 3, ks = (t >> 11) & 1, j = t >> 12;
    int c = ks * 32 + q * 8 + i;
    wA[t] = f2bf(w_conv[o * 576 + c * 9 + j]);
  }
  if (t < 18432) {
    int i = t & 7, m = (t >> 3) & 31, q = (t >> 8) & 3, ks = (t >> 10) & 1, j = t >> 11;
    int c = ks * 32 + q * 8 + i;
    wOf[t] = (m < 27) ? f2bf(w_off[(m * 64 + c) * 9 + j]) : (short)0;
  }
}

// NCHW f32 -> NHWC bf16 via LDS tile (proven in round 2)
__global__ __launch_bounds__(256) void xpose_x(const float* __restrict__ x,
                                               short* __restrict__ x_t) {
  __shared__ float lt[64][65];
  int bi  = blockIdx.x >> 8;
  int hw0 = (blockIdx.x & 255) * 64;
  int t = threadIdx.x;
  const float* xb = x + bi * (CIN_ * IMG_) + hw0;
#pragma unroll
  for (int i = 0; i < 16; ++i) {
    int c = i * 4 + (t >> 6), px = t & 63;
    lt[c][px] = xb[c * IMG_ + px];
  }
  __syncthreads();
  short* ob = x_t + (size_t)(bi * IMG_ + hw0) * 64;
#pragma unroll
  for (int i = 0; i < 16; ++i) {
    int px = i * 4 + (t >> 6), c = t & 63;
    ob[px * 64 + c] = f2bf(lt[c][px]);
  }
}

// offset conv, fragment-direct, no LDS, no barriers.
__global__ __launch_bounds__(256) void offk(const short* __restrict__ x_t,
                                            const short* __restrict__ wOf,
                                            const float* __restrict__ b_off,
                                            short* __restrict__ ob2) {
  int bi  = blockIdx.x >> 8;
  int hw0 = (blockIdx.x & 255) * 64;
  int h   = hw0 >> 7;
  int w0  = hw0 & 127;
  int t   = threadIdx.x;
  int wv = t >> 6, l = t & 63;
  int col = l & 15, q = l >> 4;
  int px_local = wv * 16 + col;
  int wwb = w0 + px_local;

  const short* xb = x_t + (size_t)bi * (IMG_ * 64);
  const short* wq = wOf + q * 256 + col * 8;

  f32x4 acc0 = {0.f, 0.f, 0.f, 0.f};
  f32x4 acc1 = {0.f, 0.f, 0.f, 0.f};

#pragma unroll
  for (int j = 0; j < 9; ++j) {
    int hh = h + j / 3 - 1;
    int ww = wwb + j % 3 - 1;
    s16x8 b0 = {0,0,0,0,0,0,0,0}, b1 = {0,0,0,0,0,0,0,0};
    if (hh >= 0 && hh < HW_ && ww >= 0 && ww < HW_) {
      const short* src = xb + (hh * HW_ + ww) * 64 + q * 8;
      b0 = *(const s16x8*)(src);
      b1 = *(const s16x8*)(src + 32);
    }
    const short* wj = wq + j * 2048;
    s16x8 a00 = *(const s16x8*)(wj);
    s16x8 a01 = *(const s16x8*)(wj + 128);
    s16x8 a10 = *(const s16x8*)(wj + 1024);
    s16x8 a11 = *(const s16x8*)(wj + 1024 + 128);
    acc0 = __builtin_amdgcn_mfma_f32_16x16x32_bf16(a00, b0, acc0, 0, 0, 0);
    acc1 = __builtin_amdgcn_mfma_f32_16x16x32_bf16(a01, b0, acc1, 0, 0, 0);
    acc0 = __builtin_amdgcn_mfma_f32_16x16x32_bf16(a10, b1, acc0, 0, 0, 0);
    acc1 = __builtin_amdgcn_mfma_f32_16x16x32_bf16(a11, b1, acc1, 0, 0, 0);
  }

  short* op = ob2 + (size_t)(bi * IMG_ + hw0 + px_local) * 32;
#pragma unroll
  for (int r = 0; r < 4; ++r) {
    int ch = q * 4 + r;
    op[ch] = f2bf(acc0[r] + b_off[ch]);
  }
#pragma unroll
  for (int r = 0; r < 4; ++r) {
    int ch = 16 + q * 4 + r;
    if (ch < 27) {
      float v = acc1[r] + b_off[ch];
      if (ch >= 18) v = 1.f / (1.f + __expf(-v));
      op[ch] = f2bf(v);
    }
  }
}

// fused deformable sample -> MFMA, fragment-direct, no LDS, no barriers.
__global__ __launch_bounds__(256) void dfk(const short* __restrict__ x_t,
                                           const short* __restrict__ ob2,
                                           const short* __restrict__ wA,
                                           float* __restrict__ out) {
  int bi  = blockIdx.x >> 8;
  int hw0 = (blockIdx.x & 255) * 64;
  int t = threadIdx.x;
  int wv = t >> 6, l = t & 63;
  int col = l & 15, q = l >> 4;
  int px_local = wv * 16 + col;
  int p = hw0 + px_local;
  int h = p >> 7, w = p & 127;

  const short* xb = x_t + (size_t)bi * (IMG_ * 64);
  const short* wq = wA + q * 512 + col * 8;

  // prefetch the full 64B offset row for this pixel (27 bf16 used)
  const uint4* obw = (const uint4*)(ob2 + (size_t)(bi * IMG_ + p) * 32);
  uint4 r0 = obw[0], r1 = obw[1], r2 = obw[2], r3 = obw[3];
  unsigned ow[16] = {r0.x, r0.y, r0.z, r0.w, r1.x, r1.y, r1.z, r1.w,
                     r2.x, r2.y, r2.z, r2.w, r3.x, r3.y, r3.z, r3.w};

  f32x4 acc[4];
#pragma unroll
  for (int ms = 0; ms < 4; ++ms) acc[ms] = (f32x4){0.f, 0.f, 0.f, 0.f};

#pragma unroll
  for (int j = 0; j < 9; ++j) {
    const int e1 = j, e2 = 9 + j, e3 = 18 + j;
    float o1 = bf2f((short)(ow[e1 >> 1] >> ((e1 & 1) << 4)));
    float o2 = bf2f((short)(ow[e2 >> 1] >> ((e2 & 1) << 4)));
    float mk = bf2f((short)(ow[e3 >> 1] >> ((e3 & 1) << 4)));

    float pxf = o1 + (float)(w + (j % 3) - 1);
    float pyf = o2 + (float)(h + (j / 3) - 1);
    float fx = floorf(pxf), fy = floorf(pyf);
    int   x0 = (int)fx,   y0 = (int)fy;
    float ax = pxf - fx, ay = pyf - fy;
    float bx = 1.f - ax, by = 1.f - ay;

    bool vx0 = (x0 >= 0)  && (x0 < HW_);
    bool vx1 = (x0 >= -1) && (x0 < HW_ - 1);
    bool vy0 = (y0 >= 0)  && (y0 < HW_);
    bool vy1 = (y0 >= -1) && (y0 < HW_ - 1);

    float w00 = by * bx * mk * ((vy0 && vx0) ? 1.f : 0.f);
    float w01 = by * ax * mk * ((vy0 && vx1) ? 1.f : 0.f);
    float w10 = ay * bx * mk * ((vy1 && vx0) ? 1.f : 0.f);
    float w11 = ay * ax * mk * ((vy1 && vx1) ? 1.f : 0.f);

    int xc0 = min(max(x0, 0), HW_ - 1), xc1 = min(max(x0 + 1, 0), HW_ - 1);
    int yc0 = min(max(y0, 0), HW_ - 1), yc1 = min(max(y0 + 1, 0), HW_ - 1);

    const short* p00 = xb + (yc0 * HW_ + xc0) * 64 + q * 8;
    const short* p01 = xb + (yc0 * HW_ + xc1) * 64 + q * 8;
    const short* p10 = xb + (yc1 * HW_ + xc0) * 64 + q * 8;
    const short* p11 = xb + (yc1 * HW_ + xc1) * 64 + q * 8;

    s16x8 c00a = *(const s16x8*)(p00), c00b = *(const s16x8*)(p00 + 32);
    s16x8 c01a = *(const s16x8*)(p01), c01b = *(const s16x8*)(p01 + 32);
    s16x8 c10a = *(const s16x8*)(p10), c10b = *(const s16x8*)(p10 + 32);
    s16x8 c11a = *(const s16x8*)(p11), c11b = *(const s16x8*)(p11 + 32);

    union { unsigned u[4]; s16x8 v; } F0, F1;
#pragma unroll
    for (int kk = 0; kk < 4; ++kk) {
      float va = w00 * bf2f(c00a[2*kk])     + w01 * bf2f(c01a[2*kk])
               + w10 * bf2f(c10a[2*kk])     + w11 * bf2f(c11a[2*kk]);
      float vb = w00 * bf2f(c00a[2*kk+1])   + w01 * bf2f(c01a[2*kk+1])
               + w10 * bf2f(c10a[2*kk+1])   + w11 * bf2f(c11a[2*kk+1]);
      F0.u[kk] = pk_bf16(va, vb);
      float vc = w00 * bf2f(c00b[2*kk])     + w01 * bf2f(c01b[2*kk])
               + w10 * bf2f(c10b[2*kk])     + w11 * bf2f(c11b[2*kk]);
      float vd = w00 * bf2f(c00b[2*kk+1])   + w01 * bf2f(c01b[2*kk+1])
               + w10 * bf2f(c10b[2*kk+1])   + w11 * bf2f(c11b[2*kk+1]);
      F1.u[kk] = pk_bf16(vc, vd);
    }

    const short* wj = wq + j * 4096;
#pragma unroll
    for (int ms = 0; ms < 4; ++ms) {
      s16x8 a0 = *(const s16x8*)(wj + ms * 128);
      acc[ms] = __builtin_amdgcn_mfma_f32_16x16x32_bf16(a0, F0.v, acc[ms], 0, 0, 0);
    }
#pragma unroll
    for (int ms = 0; ms < 4; ++ms) {
      s16x8 a1 = *(const s16x8*)(wj + 2048 + ms * 128);
      acc[ms] = __builtin_amdgcn_mfma_f32_16x16x32_bf16(a1, F1.v, acc[ms], 0, 0, 0);
    }
  }

  float* op = out + (size_t)bi * (CIN_ * IMG_) + p;
#pragma unroll
  for (int ms = 0; ms < 4; ++ms)
#pragma unroll
    for (int r = 0; r < 4; ++r)
      op[(ms * 16 + q * 4 + r) * IMG_] = acc[ms][r];
}

extern "C" void kernel_launch(void* const* d_in, const int* in_sizes, int n_in,
                              void* d_out, int out_size, void* d_ws, size_t ws_size,
                              hipStream_t stream) {
  const float* x      = (const float*)d_in[0];
  const float* w_off  = (const float*)d_in[1];
  const float* b_off  = (const float*)d_in[2];
  const float* w_conv = (const float*)d_in[3];
  float* out = (float*)d_out;

  char* ws = (char*)d_ws;
  short* wOf = (short*)(ws);
  short* wA  = (short*)(ws + 36864);
  short* ob2 = (short*)(ws + 110592);
  short* x_t = (short*)(ws + 8499200);

  hipLaunchKernelGGL(prep_w,  dim3(144),  dim3(256), 0, stream, w_off, w_conv, wOf, wA);
  hipLaunchKernelGGL(xpose_x, dim3(2048), dim3(256), 0, stream, x, x_t);
  hipLaunchKernelGGL(offk,    dim3(2048), dim3(256), 0, stream, x_t, wOf, b_off, ob2);
  hipLaunchKernelGGL(dfk,     dim3(2048), dim3(256), 0, stream, x_t, ob2, wA, out);
}

// Round 5
// 192.122 us; speedup vs baseline: 1.4467x; 1.0363x over previous
//
#include <hip/hip_runtime.h>
#include <math.h>

#define HW_   128
#define CIN_  64
#define IMG_  (HW_ * HW_)       // 16384

typedef short  s16x8 __attribute__((ext_vector_type(8)));
typedef float  f32x4 __attribute__((ext_vector_type(4)));

__device__ __forceinline__ float bf2f(short u) {
  union { unsigned i; float f; } v;
  v.i = ((unsigned)(unsigned short)u) << 16;
  return v.f;
}
__device__ __forceinline__ short f2bf(float f) {
  union { float f; unsigned i; } v; v.f = f;
  unsigned r = (v.i + 0x7fffu + ((v.i >> 16) & 1u)) >> 16;   // RNE
  return (short)r;
}
// pack two f32 -> bf16 pair (lo = a, hi = b), RNE
__device__ __forceinline__ unsigned pk_bf16(float a, float b) {
  union { float f; unsigned u; } ua, ub; ua.f = a; ub.f = b;
  unsigned ra = ua.u + 0x7fffu + ((ua.u >> 16) & 1u);
  unsigned rb = ub.u + 0x7fffu + ((ub.u >> 16) & 1u);
  return __builtin_amdgcn_perm(rb, ra, 0x07060302u);
}

// ws layout (bytes):
//   [0,       36864)    wOf bf16 [j:9][ks:2][q:4][m:32][i:8]  (A-frag order, m>=27 zero)
//   [36864,   110592)   wA  bf16 [j:9][ks:2][q:4][o:64][i:8]  (A-frag order)
//   [110592,  16887808) x_t bf16 [8][128][128][64] (NHWC)

__global__ __launch_bounds__(256) void prep_w(const float* __restrict__ w_off,
                                              const float* __restrict__ w_conv,
                                              short* __restrict__ wOf,
                                              short* __restrict__ wA) {
  int t = blockIdx.x * 256 + threadIdx.x;
  if (t < 36864) {
    int i = t & 7, o = (t >> 3) & 63, q = (t >> 9) & 3, ks = (t >> 11) & 1, j = t >> 12;
    int c = ks * 32 + q * 8 + i;
    wA[t] = f2bf(w_conv[o * 576 + c * 9 + j]);
  }
  if (t < 18432) {
    int i = t & 7, m = (t >> 3) & 31, q = (t >> 8) & 3, ks = (t >> 10) & 1, j = t >> 11;
    int c = ks * 32 + q * 8 + i;
    wOf[t] = (m < 27) ? f2bf(w_off[(m * 64 + c) * 9 + j]) : (short)0;
  }
}

// NCHW f32 -> NHWC bf16 via LDS tile
__global__ __launch_bounds__(256) void xpose_x(const float* __restrict__ x,
                                               short* __restrict__ x_t) {
  __shared__ float lt[64][65];
  int bi  = blockIdx.x >> 8;
  int hw0 = (blockIdx.x & 255) * 64;
  int t = threadIdx.x;
  const float* xb = x + bi * (CIN_ * IMG_) + hw0;
#pragma unroll
  for (int i = 0; i < 16; ++i) {
    int c = i * 4 + (t >> 6), px = t & 63;
    lt[c][px] = xb[c * IMG_ + px];
  }
  __syncthreads();
  short* ob = x_t + (size_t)(bi * IMG_ + hw0) * 64;
#pragma unroll
  for (int i = 0; i < 16; ++i) {
    int px = i * 4 + (t >> 6), c = t & 63;
    ob[px * 64 + c] = f2bf(lt[c][px]);
  }
}

// Fused: offset-conv (MFMA) -> LDS offset exchange -> pipelined deformable
// sample -> MFMA GEMM. One barrier total.
__global__ __launch_bounds__(256, 4) void dfuse(const short* __restrict__ x_t,
                                                const short* __restrict__ wOf,
                                                const float* __restrict__ b_off,
                                                const short* __restrict__ wA,
                                                float* __restrict__ out) {
  __shared__ short obx[64 * 32];   // [px][ch0..31] bf16: o1(0-8) o2(9-17) sig(18-26)

  int bi  = blockIdx.x >> 8;
  int hw0 = (blockIdx.x & 255) * 64;
  int h   = hw0 >> 7;
  int w0  = hw0 & 127;
  int t   = threadIdx.x;
  int wv = t >> 6, l = t & 63;
  int col = l & 15, q = l >> 4;
  int px_local = wv * 16 + col;
  int p = hw0 + px_local;
  int w = w0 + px_local;

  const short* xb = x_t + (size_t)bi * (IMG_ * 64);

  // ---------------- phase 1: offset conv ----------------
  {
    const short* wq = wOf + q * 256 + col * 8;
    f32x4 a0v = {0.f, 0.f, 0.f, 0.f};
    f32x4 a1v = {0.f, 0.f, 0.f, 0.f};
#pragma unroll
    for (int j = 0; j < 9; ++j) {
      int hh = h + j / 3 - 1;
      int ww = w + j % 3 - 1;
      s16x8 b0 = {0,0,0,0,0,0,0,0}, b1 = {0,0,0,0,0,0,0,0};
      if (hh >= 0 && hh < HW_ && ww >= 0 && ww < HW_) {
        const short* src = xb + (hh * HW_ + ww) * 64 + q * 8;
        b0 = *(const s16x8*)(src);
        b1 = *(const s16x8*)(src + 32);
      }
      const short* wj = wq + j * 2048;
      s16x8 a00 = *(const s16x8*)(wj);
      s16x8 a01 = *(const s16x8*)(wj + 128);
      s16x8 a10 = *(const s16x8*)(wj + 1024);
      s16x8 a11 = *(const s16x8*)(wj + 1024 + 128);
      a0v = __builtin_amdgcn_mfma_f32_16x16x32_bf16(a00, b0, a0v, 0, 0, 0);
      a1v = __builtin_amdgcn_mfma_f32_16x16x32_bf16(a01, b0, a1v, 0, 0, 0);
      a0v = __builtin_amdgcn_mfma_f32_16x16x32_bf16(a10, b1, a0v, 0, 0, 0);
      a1v = __builtin_amdgcn_mfma_f32_16x16x32_bf16(a11, b1, a1v, 0, 0, 0);
    }
    short* od = obx + px_local * 32;
#pragma unroll
    for (int r = 0; r < 4; ++r) {
      int ch = q * 4 + r;
      od[ch] = f2bf(a0v[r] + b_off[ch]);
    }
#pragma unroll
    for (int r = 0; r < 4; ++r) {
      int ch = 16 + q * 4 + r;
      if (ch < 27) {
        float v = a1v[r] + b_off[ch];
        if (ch >= 18) v = 1.f / (1.f + __expf(-v));
        od[ch] = f2bf(v);
      }
    }
  }
  __syncthreads();

  // ---------------- phase 2: pipelined sampling + GEMM ----------------
  const uint4* obw = (const uint4*)(obx + px_local * 32);
  uint4 q0 = obw[0], q1 = obw[1], q2 = obw[2], q3 = obw[3];
  unsigned ow[16] = {q0.x, q0.y, q0.z, q0.w, q1.x, q1.y, q1.z, q1.w,
                     q2.x, q2.y, q2.z, q2.w, q3.x, q3.y, q3.z, q3.w};

  f32x4 acc[4];
#pragma unroll
  for (int ms = 0; ms < 4; ++ms) acc[ms] = (f32x4){0.f, 0.f, 0.f, 0.f};

  const short* wq = wA + q * 512 + col * 8;

  const short* P[4];
  float W4[4];
  auto mktap = [&](int j) {
    const int e1 = j, e2 = 9 + j, e3 = 18 + j;
    float o1 = bf2f((short)(ow[e1 >> 1] >> ((e1 & 1) << 4)));
    float o2 = bf2f((short)(ow[e2 >> 1] >> ((e2 & 1) << 4)));
    float mk = bf2f((short)(ow[e3 >> 1] >> ((e3 & 1) << 4)));

    float pxf = o1 + (float)(w + (j % 3) - 1);
    float pyf = o2 + (float)(h + (j / 3) - 1);
    float fx = floorf(pxf), fy = floorf(pyf);
    int   x0 = (int)fx,   y0 = (int)fy;
    float ax = pxf - fx, ay = pyf - fy;
    float bx = 1.f - ax, by = 1.f - ay;

    bool vx0 = (x0 >= 0)  && (x0 < HW_);
    bool vx1 = (x0 >= -1) && (x0 < HW_ - 1);
    bool vy0 = (y0 >= 0)  && (y0 < HW_);
    bool vy1 = (y0 >= -1) && (y0 < HW_ - 1);

    W4[0] = by * bx * mk * ((vy0 && vx0) ? 1.f : 0.f);
    W4[1] = by * ax * mk * ((vy0 && vx1) ? 1.f : 0.f);
    W4[2] = ay * bx * mk * ((vy1 && vx0) ? 1.f : 0.f);
    W4[3] = ay * ax * mk * ((vy1 && vx1) ? 1.f : 0.f);

    int xc0 = min(max(x0, 0), HW_ - 1), xc1 = min(max(x0 + 1, 0), HW_ - 1);
    int yc0 = min(max(y0, 0), HW_ - 1), yc1 = min(max(y0 + 1, 0), HW_ - 1);
    P[0] = xb + (yc0 * HW_ + xc0) * 64 + q * 8;
    P[1] = xb + (yc0 * HW_ + xc1) * 64 + q * 8;
    P[2] = xb + (yc1 * HW_ + xc0) * 64 + q * 8;
    P[3] = xb + (yc1 * HW_ + xc1) * 64 + q * 8;
  };

  s16x8 cb[8];
  mktap(0);
#pragma unroll
  for (int cn = 0; cn < 4; ++cn) {
    cb[cn]     = *(const s16x8*)(P[cn]);
    cb[4 + cn] = *(const s16x8*)(P[cn] + 32);
  }
  float w00 = W4[0], w01 = W4[1], w10 = W4[2], w11 = W4[3];

#pragma unroll
  for (int j = 0; j < 9; ++j) {
    s16x8 cur[8];
#pragma unroll
    for (int i = 0; i < 8; ++i) cur[i] = cb[i];
    float u00 = w00, u01 = w01, u10 = w10, u11 = w11;

    if (j < 8) {
      mktap(j + 1);
#pragma unroll
      for (int cn = 0; cn < 4; ++cn) {
        cb[cn]     = *(const s16x8*)(P[cn]);
        cb[4 + cn] = *(const s16x8*)(P[cn] + 32);
      }
      w00 = W4[0]; w01 = W4[1]; w10 = W4[2]; w11 = W4[3];
    }

    union { unsigned u[4]; s16x8 v; } F0, F1;
#pragma unroll
    for (int kk = 0; kk < 4; ++kk) {
      float va = u00 * bf2f(cur[0][2*kk])   + u01 * bf2f(cur[1][2*kk])
               + u10 * bf2f(cur[2][2*kk])   + u11 * bf2f(cur[3][2*kk]);
      float vb = u00 * bf2f(cur[0][2*kk+1]) + u01 * bf2f(cur[1][2*kk+1])
               + u10 * bf2f(cur[2][2*kk+1]) + u11 * bf2f(cur[3][2*kk+1]);
      F0.u[kk] = pk_bf16(va, vb);
      float vc = u00 * bf2f(cur[4][2*kk])   + u01 * bf2f(cur[5][2*kk])
               + u10 * bf2f(cur[6][2*kk])   + u11 * bf2f(cur[7][2*kk]);
      float vd = u00 * bf2f(cur[4][2*kk+1]) + u01 * bf2f(cur[5][2*kk+1])
               + u10 * bf2f(cur[6][2*kk+1]) + u11 * bf2f(cur[7][2*kk+1]);
      F1.u[kk] = pk_bf16(vc, vd);
    }

    const short* wj = wq + j * 4096;
#pragma unroll
    for (int ms = 0; ms < 4; ++ms) {
      s16x8 a0 = *(const s16x8*)(wj + ms * 128);
      acc[ms] = __builtin_amdgcn_mfma_f32_16x16x32_bf16(a0, F0.v, acc[ms], 0, 0, 0);
    }
#pragma unroll
    for (int ms = 0; ms < 4; ++ms) {
      s16x8 a1 = *(const s16x8*)(wj + 2048 + ms * 128);
      acc[ms] = __builtin_amdgcn_mfma_f32_16x16x32_bf16(a1, F1.v, acc[ms], 0, 0, 0);
    }
  }

  float* op = out + (size_t)bi * (CIN_ * IMG_) + p;
#pragma unroll
  for (int ms = 0; ms < 4; ++ms)
#pragma unroll
    for (int r = 0; r < 4; ++r)
      op[(ms * 16 + q * 4 + r) * IMG_] = acc[ms][r];
}

extern "C" void kernel_launch(void* const* d_in, const int* in_sizes, int n_in,
                              void* d_out, int out_size, void* d_ws, size_t ws_size,
                              hipStream_t stream) {
  const float* x      = (const float*)d_in[0];
  const float* w_off  = (const float*)d_in[1];
  const float* b_off  = (const float*)d_in[2];
  const float* w_conv = (const float*)d_in[3];
  float* out = (float*)d_out;

  char* ws = (char*)d_ws;
  short* wOf = (short*)(ws);
  short* wA  = (short*)(ws + 36864);
  short* x_t = (short*)(ws + 110592);

  hipLaunchKernelGGL(prep_w,  dim3(144),  dim3(256), 0, stream, w_off, w_conv, wOf, wA);
  hipLaunchKernelGGL(xpose_x, dim3(2048), dim3(256), 0, stream, x, x_t);
  hipLaunchKernelGGL(dfuse,   dim3(2048), dim3(256), 0, stream, x_t, wOf, b_off, wA, out);
}

// Round 6
// 189.517 us; speedup vs baseline: 1.4666x; 1.0137x over previous
//
#include <hip/hip_runtime.h>
#include <math.h>

#define HW_   128
#define CIN_  64
#define IMG_  (HW_ * HW_)       // 16384

typedef short    s16x8 __attribute__((ext_vector_type(8)));
typedef float    f32x4 __attribute__((ext_vector_type(4)));
typedef float    f32x2 __attribute__((ext_vector_type(2)));
typedef unsigned u32x4 __attribute__((ext_vector_type(4)));

__device__ __forceinline__ float bf2f(short u) {
  union { unsigned i; float f; } v;
  v.i = ((unsigned)(unsigned short)u) << 16;
  return v.f;
}
__device__ __forceinline__ short f2bf(float f) {
  union { float f; unsigned i; } v; v.f = f;
  unsigned r = (v.i + 0x7fffu + ((v.i >> 16) & 1u)) >> 16;   // RNE
  return (short)r;
}
// pack two f32 -> bf16 pair (lo = a, hi = b), RNE
__device__ __forceinline__ unsigned pk_bf16(float a, float b) {
  union { float f; unsigned u; } ua, ub; ua.f = a; ub.f = b;
  unsigned ra = ua.u + 0x7fffu + ((ua.u >> 16) & 1u);
  unsigned rb = ub.u + 0x7fffu + ((ub.u >> 16) & 1u);
  return __builtin_amdgcn_perm(rb, ra, 0x07060302u);
}
// unpack bf16 pair -> float2 {lo, hi}
__device__ __forceinline__ f32x2 up2(unsigned d) {
  union { unsigned u; float f; } lo, hi;
  lo.u = d << 16; hi.u = d & 0xffff0000u;
  return (f32x2){lo.f, hi.f};
}

// ws layout (bytes):
//   [0,       36864)    wOf bf16 [j:9][ks:2][q:4][m:32][i:8]  (A-frag order, m>=27 zero)
//   [36864,   110592)   wA  bf16 [j:9][ks:2][q:4][o:64][i:8]  (A-frag order)
//   [110592,  16887808) x_t bf16 [8][128][128][64] (NHWC)

// blocks 0..2047: NCHW f32 -> NHWC bf16 transpose; blocks 2048..: weight prep
__global__ __launch_bounds__(256) void prep_all(const float* __restrict__ x,
                                                const float* __restrict__ w_off,
                                                const float* __restrict__ w_conv,
                                                short* __restrict__ x_t,
                                                short* __restrict__ wOf,
                                                short* __restrict__ wA) {
  __shared__ float lt[64][65];
  if (blockIdx.x >= 2048) {
    int t = (blockIdx.x - 2048) * 256 + threadIdx.x;
    if (t < 36864) {
      int i = t & 7, o = (t >> 3) & 63, q = (t >> 9) & 3, ks = (t >> 11) & 1, j = t >> 12;
      int c = ks * 32 + q * 8 + i;
      wA[t] = f2bf(w_conv[o * 576 + c * 9 + j]);
    }
    if (t < 18432) {
      int i = t & 7, m = (t >> 3) & 31, q = (t >> 8) & 3, ks = (t >> 10) & 1, j = t >> 11;
      int c = ks * 32 + q * 8 + i;
      wOf[t] = (m < 27) ? f2bf(w_off[(m * 64 + c) * 9 + j]) : (short)0;
    }
    return;
  }
  int bi  = blockIdx.x >> 8;
  int hw0 = (blockIdx.x & 255) * 64;
  int t = threadIdx.x;
  const float* xb = x + bi * (CIN_ * IMG_) + hw0;
#pragma unroll
  for (int i = 0; i < 16; ++i) {
    int c = i * 4 + (t >> 6), px = t & 63;
    lt[c][px] = xb[c * IMG_ + px];
  }
  __syncthreads();
  short* ob = x_t + (size_t)(bi * IMG_ + hw0) * 64;
  // 4 channels/thread -> 8B stores
#pragma unroll
  for (int i = 0; i < 4; ++i) {
    int px = i * 16 + (t >> 4), c0 = (t & 15) * 4;
    unsigned lo = pk_bf16(lt[c0][px], lt[c0 + 1][px]);
    unsigned hi = pk_bf16(lt[c0 + 2][px], lt[c0 + 3][px]);
    *(uint2*)&ob[px * 64 + c0] = make_uint2(lo, hi);
  }
}

// Fused: offset-conv (MFMA) -> LDS offset exchange -> address-precomputed,
// pipelined deformable sample -> MFMA GEMM. One barrier total.
__global__ __launch_bounds__(256)
__attribute__((amdgpu_waves_per_eu(2, 4)))
void dfuse(const short* __restrict__ x_t,
           const short* __restrict__ wOf,
           const float* __restrict__ b_off,
           const short* __restrict__ wA,
           float* __restrict__ out) {
  __shared__ short obx[64 * 32];   // [px][ch0..31] bf16: o1(0-8) o2(9-17) sig(18-26)

  int bi  = blockIdx.x >> 8;
  int hw0 = (blockIdx.x & 255) * 64;
  int t   = threadIdx.x;
  int wv = t >> 6, l = t & 63;
  int col = l & 15, q = l >> 4;
  int px_local = wv * 16 + col;
  int p = hw0 + px_local;
  int h = p >> 7, w = p & 127;

  const short* xb = x_t + (size_t)bi * (IMG_ * 64);

  // ---------------- phase 1: offset conv ----------------
  {
    // precompute clamped offsets + validity masks so loads are hoistable
    int      p1off[9];
    unsigned p1m[9];
#pragma unroll
    for (int j = 0; j < 9; ++j) {
      int hh = h + j / 3 - 1, ww = w + j % 3 - 1;
      bool v = (hh >= 0) && (hh < HW_) && (ww >= 0) && (ww < HW_);
      int hc = min(max(hh, 0), HW_ - 1), wc = min(max(ww, 0), HW_ - 1);
      p1off[j] = (hc * HW_ + wc) * 64 + q * 8;
      p1m[j] = v ? 0xffffffffu : 0u;
    }
    const short* wq = wOf + q * 256 + col * 8;
    f32x4 a0v = {0.f, 0.f, 0.f, 0.f};
    f32x4 a1v = {0.f, 0.f, 0.f, 0.f};
#pragma unroll
    for (int j = 0; j < 9; ++j) {
      u32x4 b0u = *(const u32x4*)(xb + p1off[j]);
      u32x4 b1u = *(const u32x4*)(xb + p1off[j] + 32);
      unsigned m = p1m[j];
#pragma unroll
      for (int i = 0; i < 4; ++i) { b0u[i] &= m; b1u[i] &= m; }
      union { u32x4 u; s16x8 v; } B0, B1;
      B0.u = b0u; B1.u = b1u;
      const short* wj = wq + j * 2048;
      s16x8 a00 = *(const s16x8*)(wj);
      s16x8 a01 = *(const s16x8*)(wj + 128);
      s16x8 a10 = *(const s16x8*)(wj + 1024);
      s16x8 a11 = *(const s16x8*)(wj + 1024 + 128);
      a0v = __builtin_amdgcn_mfma_f32_16x16x32_bf16(a00, B0.v, a0v, 0, 0, 0);
      a1v = __builtin_amdgcn_mfma_f32_16x16x32_bf16(a01, B0.v, a1v, 0, 0, 0);
      a0v = __builtin_amdgcn_mfma_f32_16x16x32_bf16(a10, B1.v, a0v, 0, 0, 0);
      a1v = __builtin_amdgcn_mfma_f32_16x16x32_bf16(a11, B1.v, a1v, 0, 0, 0);
    }
    short* od = obx + px_local * 32;
#pragma unroll
    for (int r = 0; r < 4; ++r) {
      int ch = q * 4 + r;
      od[ch] = f2bf(a0v[r] + b_off[ch]);
    }
#pragma unroll
    for (int r = 0; r < 4; ++r) {
      int ch = 16 + q * 4 + r;
      if (ch < 27) {
        float v = a1v[r] + b_off[ch];
        if (ch >= 18) v = 1.f / (1.f + __expf(-v));
        od[ch] = f2bf(v);
      }
    }
  }
  __syncthreads();

  // ---------------- phase 2: precompute ALL tap addresses + weights --------
  int   coff[9][4];
  float cwgt[9][4];
  {
    const uint4* obw = (const uint4*)(obx + px_local * 32);
    uint4 q0 = obw[0], q1 = obw[1], q2 = obw[2], q3 = obw[3];
    unsigned ow[16] = {q0.x, q0.y, q0.z, q0.w, q1.x, q1.y, q1.z, q1.w,
                       q2.x, q2.y, q2.z, q2.w, q3.x, q3.y, q3.z, q3.w};
#pragma unroll
    for (int j = 0; j < 9; ++j) {
      const int e1 = j, e2 = 9 + j, e3 = 18 + j;
      float o1 = bf2f((short)(ow[e1 >> 1] >> ((e1 & 1) << 4)));
      float o2 = bf2f((short)(ow[e2 >> 1] >> ((e2 & 1) << 4)));
      float mk = bf2f((short)(ow[e3 >> 1] >> ((e3 & 1) << 4)));

      float pxf = o1 + (float)(w + (j % 3) - 1);
      float pyf = o2 + (float)(h + (j / 3) - 1);
      float fx = floorf(pxf), fy = floorf(pyf);
      int   x0 = (int)fx,   y0 = (int)fy;
      float ax = pxf - fx, ay = pyf - fy;
      float bx = 1.f - ax, by = 1.f - ay;

      bool vx0 = (x0 >= 0)  && (x0 < HW_);
      bool vx1 = (x0 >= -1) && (x0 < HW_ - 1);
      bool vy0 = (y0 >= 0)  && (y0 < HW_);
      bool vy1 = (y0 >= -1) && (y0 < HW_ - 1);

      cwgt[j][0] = by * bx * mk * ((vy0 && vx0) ? 1.f : 0.f);
      cwgt[j][1] = by * ax * mk * ((vy0 && vx1) ? 1.f : 0.f);
      cwgt[j][2] = ay * bx * mk * ((vy1 && vx0) ? 1.f : 0.f);
      cwgt[j][3] = ay * ax * mk * ((vy1 && vx1) ? 1.f : 0.f);

      int xc0 = min(max(x0, 0), HW_ - 1), xc1 = min(max(x0 + 1, 0), HW_ - 1);
      int yc0 = min(max(y0, 0), HW_ - 1), yc1 = min(max(y0 + 1, 0), HW_ - 1);
      coff[j][0] = (yc0 * HW_ + xc0) * 64 + q * 8;
      coff[j][1] = (yc0 * HW_ + xc1) * 64 + q * 8;
      coff[j][2] = (yc1 * HW_ + xc0) * 64 + q * 8;
      coff[j][3] = (yc1 * HW_ + xc1) * 64 + q * 8;
    }
  }

  // ---------------- phase 3: pipelined sampling + GEMM ----------------
  f32x4 acc[4];
#pragma unroll
  for (int ms = 0; ms < 4; ++ms) acc[ms] = (f32x4){0.f, 0.f, 0.f, 0.f};

  const short* wq = wA + q * 512 + col * 8;

  u32x4 cb[8];
#pragma unroll
  for (int cn = 0; cn < 4; ++cn) {
    cb[cn]     = *(const u32x4*)(xb + coff[0][cn]);
    cb[4 + cn] = *(const u32x4*)(xb + coff[0][cn] + 32);
  }

#pragma unroll
  for (int j = 0; j < 9; ++j) {
    u32x4 cur[8];
#pragma unroll
    for (int i = 0; i < 8; ++i) cur[i] = cb[i];

    if (j < 8) {
#pragma unroll
      for (int cn = 0; cn < 4; ++cn) {
        cb[cn]     = *(const u32x4*)(xb + coff[j + 1][cn]);
        cb[4 + cn] = *(const u32x4*)(xb + coff[j + 1][cn] + 32);
      }
    }

    float u0 = cwgt[j][0], u1 = cwgt[j][1], u2 = cwgt[j][2], u3 = cwgt[j][3];
    union { unsigned u[4]; s16x8 v; } F0, F1;
#pragma unroll
    for (int i = 0; i < 4; ++i) {
      f32x2 v0 = up2(cur[0][i]) * u0;
      v0 += up2(cur[1][i]) * u1;
      v0 += up2(cur[2][i]) * u2;
      v0 += up2(cur[3][i]) * u3;
      F0.u[i] = pk_bf16(v0.x, v0.y);
      f32x2 v1 = up2(cur[4][i]) * u0;
      v1 += up2(cur[5][i]) * u1;
      v1 += up2(cur[6][i]) * u2;
      v1 += up2(cur[7][i]) * u3;
      F1.u[i] = pk_bf16(v1.x, v1.y);
    }

    const short* wj = wq + j * 4096;
#pragma unroll
    for (int ms = 0; ms < 4; ++ms) {
      s16x8 a0 = *(const s16x8*)(wj + ms * 128);
      acc[ms] = __builtin_amdgcn_mfma_f32_16x16x32_bf16(a0, F0.v, acc[ms], 0, 0, 0);
    }
#pragma unroll
    for (int ms = 0; ms < 4; ++ms) {
      s16x8 a1 = *(const s16x8*)(wj + 2048 + ms * 128);
      acc[ms] = __builtin_amdgcn_mfma_f32_16x16x32_bf16(a1, F1.v, acc[ms], 0, 0, 0);
    }
  }

  float* op = out + (size_t)bi * (CIN_ * IMG_) + p;
#pragma unroll
  for (int ms = 0; ms < 4; ++ms)
#pragma unroll
    for (int r = 0; r < 4; ++r)
      op[(ms * 16 + q * 4 + r) * IMG_] = acc[ms][r];
}

extern "C" void kernel_launch(void* const* d_in, const int* in_sizes, int n_in,
                              void* d_out, int out_size, void* d_ws, size_t ws_size,
                              hipStream_t stream) {
  const float* x      = (const float*)d_in[0];
  const float* w_off  = (const float*)d_in[1];
  const float* b_off  = (const float*)d_in[2];
  const float* w_conv = (const float*)d_in[3];
  float* out = (float*)d_out;

  char* ws = (char*)d_ws;
  short* wOf = (short*)(ws);
  short* wA  = (short*)(ws + 36864);
  short* x_t = (short*)(ws + 110592);

  hipLaunchKernelGGL(prep_all, dim3(2192), dim3(256), 0, stream, x, w_off, w_conv, x_t, wOf, wA);
  hipLaunchKernelGGL(dfuse,    dim3(2048), dim3(256), 0, stream, x_t, wOf, b_off, wA, out);
}